// Round 5
// baseline (114.118 us; speedup 1.0000x reference)
//
#include <hip/hip_runtime.h>

#define NCH 26
#define CPB 256          // cells per block
#define THREADS 256
#define TILE_FLOATS (CPB * NCH)        // 6656 floats (predict tile)

typedef __attribute__((address_space(3))) unsigned int  lds_u32_t;
typedef const __attribute__((address_space(1))) unsigned int glb_u32_t;

__device__ __forceinline__ float iou_pair_r(const float* b, const float* g) {
    const float inv_s = 1.0f / 7.0f;
    float x1 = b[0] * inv_s - b[2] * 0.5f;
    float y1 = b[1] * inv_s - b[3] * 0.5f;
    float x2 = b[0] * inv_s + b[2] * 0.5f;
    float y2 = b[1] * inv_s + b[3] * 0.5f;
    float u1 = g[0] * inv_s - g[2] * 0.5f;
    float v1 = g[1] * inv_s - g[3] * 0.5f;
    float u2 = g[0] * inv_s + g[2] * 0.5f;
    float v2 = g[1] * inv_s + g[3] * 0.5f;
    float a1 = (x2 - x1) * (y2 - y1);
    float a2 = (u2 - u1) * (v2 - v1);
    float left   = fmaxf(x1, u1);
    float right  = fminf(x2, u2);
    float top    = fmaxf(y1, v1);
    float bottom = fminf(y2, v2);
    bool valid = (left < right) && (top < bottom);
    float inter = valid ? (right - left) * (bottom - top) : 0.0f;
    float uni = a1 + a2 - inter;
    return valid ? inter / uni : 0.0f;
}

__global__ __launch_bounds__(THREADS) void yolo_loss_main(
        const float* __restrict__ predict,
        const float* __restrict__ label,
        float* __restrict__ out,
        float inv_n,
        int n_cells) {
    __shared__ float sp[TILE_FLOATS];   // predict tile only: 26.6 KB -> 6 blocks/CU

    const int tid = threadIdx.x;
    const int bid = blockIdx.x;
    const int wave = tid >> 6;
    const int lane = tid & 63;
    const long long base = (long long)bid * TILE_FLOATS;   // float index
    const long long total = (long long)n_cells * NCH;
    const bool full_tile = (base + TILE_FLOATS <= total);

    if (full_tile) {
        // Direct global->LDS DMA (width 16), linear layout: chunk c covers
        // bytes [c*1024, c*1024+1024) in both global tile and LDS.
        const char* gp = (const char*)(predict + base);
        #pragma unroll
        for (int c = 0; c < 7; ++c) {
            int chunk = wave + 4 * c;          // 4 waves cover 26 chunks
            if (chunk < 26) {
                int off = chunk * 1024 + lane * 16;
                __builtin_amdgcn_global_load_lds(
                    (glb_u32_t*)(gp + off),
                    (lds_u32_t*)((char*)sp + off), 16, 0, 0);
            }
        }
    } else {
        for (int i = tid; i < TILE_FLOATS; i += THREADS) {
            long long g = base + i;
            sp[i] = (g < total) ? predict[g] : 0.0f;
        }
    }

    // Label: per-thread direct global loads (L3-hot after harness restore).
    // Only channels 0..5 and 10..25 are needed; record stride 104 B is
    // 8-aligned so float2 at even channel offsets is legal.
    float l[NCH];
    long long cell = (long long)bid * CPB + tid;
    if (cell < n_cells) {
        const float* lb = label + cell * NCH;
        const float2* lv = (const float2*)lb;
        float2 t0 = lv[0];  l[0] = t0.x; l[1] = t0.y;
        float2 t1 = lv[1];  l[2] = t1.x; l[3] = t1.y;
        l[4] = lb[4];
        #pragma unroll
        for (int k = 5; k < 13; ++k) {          // channels 10..25
            float2 t = lv[k];
            l[2 * k] = t.x; l[2 * k + 1] = t.y;
        }
    }

    __syncthreads();   // waits DMA (vmcnt) + barrier

    float partial = 0.0f;
    if (cell < n_cells) {
        float p[NCH];
        const float2* pv = (const float2*)&sp[tid * NCH];
        #pragma unroll
        for (int k = 0; k < 13; ++k) {
            float2 a = pv[k]; p[2 * k] = a.x; p[2 * k + 1] = a.y;
        }

        float conf_lab = l[4];
        float coord_m = (conf_lab > 0.0f) ? 1.0f : 0.0f;
        float noobj_m = (conf_lab == 0.0f) ? 1.0f : 0.0f;

        float acc_noobj = noobj_m * (p[4] * p[4] + p[9] * p[9]);

        float class_s = 0.0f;
        #pragma unroll
        for (int k = 10; k < 26; ++k) {
            float d = p[k] - l[k];
            class_s += d * d;
        }

        float iou1 = iou_pair_r(p + 0, l);
        float iou2 = iou_pair_r(p + 5, l);
        bool pick1 = iou1 > iou2;

        float s0 = pick1 ? p[0] : p[5];
        float s1 = pick1 ? p[1] : p[6];
        float s2 = pick1 ? p[2] : p[7];
        float s3 = pick1 ? p[3] : p[8];
        float dx = s0 - l[0];
        float dy = s1 - l[1];
        float dw = sqrtf(s2) - sqrtf(l[2]);
        float dh = sqrtf(s3) - sqrtf(l[3]);
        float coord_cell = dx * dx + dy * dy + dw * dw + dh * dh;

        float csel   = pick1 ? p[4] : p[9];
        float iousel = pick1 ? iou1 : iou2;
        float t = csel - iousel;
        float obj_c = t * t;

        float cother = pick1 ? p[9] : p[4];
        acc_noobj += coord_m * cother * cother;

        partial = 5.0f * coord_m * coord_cell
                + coord_m * obj_c
                + 0.5f * acc_noobj
                + coord_m * class_s;
    }

    // block reduction: wave64 shuffle, then cross-wave LDS
    #pragma unroll
    for (int off = 32; off > 0; off >>= 1)
        partial += __shfl_down(partial, off, 64);

    __shared__ float wsum[THREADS / 64];
    if ((tid & 63) == 0) wsum[tid >> 6] = partial;
    __syncthreads();
    if (tid == 0) {
        float s = 0.0f;
        #pragma unroll
        for (int w = 0; w < THREADS / 64; ++w) s += wsum[w];
        atomicAdd(out, s * inv_n);     // device-scope by default
    }
}

extern "C" void kernel_launch(void* const* d_in, const int* in_sizes, int n_in,
                              void* d_out, int out_size, void* d_ws, size_t ws_size,
                              hipStream_t stream) {
    const float* predict = (const float*)d_in[0];
    const float* label   = (const float*)d_in[1];
    float* out = (float*)d_out;

    int total   = in_sizes[0];         // B*7*7*26
    int n_cells = total / NCH;         // B*49
    int N = n_cells / 49;              // batch size
    int nblocks = (n_cells + CPB - 1) / CPB;

    hipMemsetAsync(out, 0, sizeof(float) * out_size, stream);
    yolo_loss_main<<<nblocks, THREADS, 0, stream>>>(
        predict, label, out, 1.0f / (float)N, n_cells);
}

// Round 10
// 112.285 us; speedup vs baseline: 1.0163x; 1.0163x over previous
//
#include <hip/hip_runtime.h>

#define NCH 26
#define CPB 256          // cells per block
#define THREADS 256
#define TILE_FLOATS (CPB * NCH)        // 6656 floats per array

typedef __attribute__((address_space(3))) unsigned int  lds_u32_t;
typedef const __attribute__((address_space(1))) unsigned int glb_u32_t;

__device__ __forceinline__ float iou_pair_r(const float* b, const float* g) {
    const float inv_s = 1.0f / 7.0f;
    float x1 = b[0] * inv_s - b[2] * 0.5f;
    float y1 = b[1] * inv_s - b[3] * 0.5f;
    float x2 = b[0] * inv_s + b[2] * 0.5f;
    float y2 = b[1] * inv_s + b[3] * 0.5f;
    float u1 = g[0] * inv_s - g[2] * 0.5f;
    float v1 = g[1] * inv_s - g[3] * 0.5f;
    float u2 = g[0] * inv_s + g[2] * 0.5f;
    float v2 = g[1] * inv_s + g[3] * 0.5f;
    float a1 = (x2 - x1) * (y2 - y1);
    float a2 = (u2 - u1) * (v2 - v1);
    float left   = fmaxf(x1, u1);
    float right  = fminf(x2, u2);
    float top    = fmaxf(y1, v1);
    float bottom = fminf(y2, v2);
    bool valid = (left < right) && (top < bottom);
    float inter = valid ? (right - left) * (bottom - top) : 0.0f;
    float uni = a1 + a2 - inter;
    return valid ? inter / uni : 0.0f;
}

__global__ __launch_bounds__(THREADS) void yolo_loss_main(
        const float* __restrict__ predict,
        const float* __restrict__ label,
        float* __restrict__ out,
        float inv_n,
        int n_cells) {
    __shared__ float sp[TILE_FLOATS];
    __shared__ float sl[TILE_FLOATS];

    const int tid = threadIdx.x;
    const int bid = blockIdx.x;
    const int wave = tid >> 6;
    const int lane = tid & 63;
    const long long base = (long long)bid * TILE_FLOATS;   // float index
    const long long total = (long long)n_cells * NCH;

    if (base + TILE_FLOATS <= total) {
        // Direct global->LDS DMA (width 16), linear layout: chunk c covers
        // bytes [c*1024, c*1024+1024) in both the global tile and LDS
        // (wave-uniform base + lane*16 — exactly the supported pattern).
        const char* gp = (const char*)(predict + base);
        const char* gl = (const char*)(label + base);
        #pragma unroll
        for (int c = 0; c < 7; ++c) {
            int chunk = wave + 4 * c;          // 4 waves cover 26 chunks
            if (chunk < 26) {
                int off = chunk * 1024 + lane * 16;
                __builtin_amdgcn_global_load_lds(
                    (glb_u32_t*)(gp + off),
                    (lds_u32_t*)((char*)sp + off), 16, 0, 0);
                __builtin_amdgcn_global_load_lds(
                    (glb_u32_t*)(gl + off),
                    (lds_u32_t*)((char*)sl + off), 16, 0, 0);
            }
        }
    } else {
        // tail block (not hit for B=8192): guarded scalar staging
        for (int i = tid; i < TILE_FLOATS; i += THREADS) {
            long long g = base + i;
            sp[i] = (g < total) ? predict[g] : 0.0f;
            sl[i] = (g < total) ? label[g] : 0.0f;
        }
    }
    __syncthreads();   // compiler emits s_waitcnt vmcnt(0) before s_barrier

    float partial = 0.0f;
    long long cell = (long long)bid * CPB + tid;
    if (cell < n_cells) {
        // vectorized LDS->reg: 13 x float2 per array (104B stride, 8-aligned)
        float p[NCH], l[NCH];
        const float2* pv = (const float2*)&sp[tid * NCH];
        const float2* lv = (const float2*)&sl[tid * NCH];
        #pragma unroll
        for (int k = 0; k < 13; ++k) {
            float2 a = pv[k]; p[2 * k] = a.x; p[2 * k + 1] = a.y;
            float2 b = lv[k]; l[2 * k] = b.x; l[2 * k + 1] = b.y;
        }

        float conf_lab = l[4];
        float coord_m = (conf_lab > 0.0f) ? 1.0f : 0.0f;
        float noobj_m = (conf_lab == 0.0f) ? 1.0f : 0.0f;

        float acc_noobj = noobj_m * (p[4] * p[4] + p[9] * p[9]);

        float class_s = 0.0f;
        #pragma unroll
        for (int k = 10; k < 26; ++k) {
            float d = p[k] - l[k];
            class_s += d * d;
        }

        float iou1 = iou_pair_r(p + 0, l);
        float iou2 = iou_pair_r(p + 5, l);
        bool pick1 = iou1 > iou2;

        float s0 = pick1 ? p[0] : p[5];
        float s1 = pick1 ? p[1] : p[6];
        float s2 = pick1 ? p[2] : p[7];
        float s3 = pick1 ? p[3] : p[8];
        float dx = s0 - l[0];
        float dy = s1 - l[1];
        float dw = sqrtf(s2) - sqrtf(l[2]);
        float dh = sqrtf(s3) - sqrtf(l[3]);
        float coord_cell = dx * dx + dy * dy + dw * dw + dh * dh;

        float csel   = pick1 ? p[4] : p[9];
        float iousel = pick1 ? iou1 : iou2;
        float t = csel - iousel;
        float obj_c = t * t;

        float cother = pick1 ? p[9] : p[4];
        acc_noobj += coord_m * cother * cother;

        partial = 5.0f * coord_m * coord_cell
                + coord_m * obj_c
                + 0.5f * acc_noobj
                + coord_m * class_s;
    }

    // block reduction: wave64 shuffle, then cross-wave LDS
    #pragma unroll
    for (int off = 32; off > 0; off >>= 1)
        partial += __shfl_down(partial, off, 64);

    __shared__ float wsum[THREADS / 64];
    if ((tid & 63) == 0) wsum[tid >> 6] = partial;
    __syncthreads();
    if (tid == 0) {
        float s = 0.0f;
        #pragma unroll
        for (int w = 0; w < THREADS / 64; ++w) s += wsum[w];
        atomicAdd(out, s * inv_n);     // device-scope by default; 1568 adds total
    }
}

extern "C" void kernel_launch(void* const* d_in, const int* in_sizes, int n_in,
                              void* d_out, int out_size, void* d_ws, size_t ws_size,
                              hipStream_t stream) {
    const float* predict = (const float*)d_in[0];
    const float* label   = (const float*)d_in[1];
    float* out = (float*)d_out;

    int total   = in_sizes[0];         // B*7*7*26
    int n_cells = total / NCH;         // B*49
    int N = n_cells / 49;              // batch size
    int nblocks = (n_cells + CPB - 1) / CPB;

    hipMemsetAsync(out, 0, sizeof(float) * out_size, stream);
    yolo_loss_main<<<nblocks, THREADS, 0, stream>>>(
        predict, label, out, 1.0f / (float)N, n_cells);
}

// Round 11
// 105.940 us; speedup vs baseline: 1.0772x; 1.0599x over previous
//
#include <hip/hip_runtime.h>

#define NCH 26
#define TCELLS 128                      // cells per wave-tile
#define TILE_FLOATS (TCELLS * NCH)      // 3328 floats = 13312 B per array
#define GRID_MAIN 768                   // 256 CU x 3 resident (52 KB LDS each)

typedef __attribute__((address_space(3))) unsigned int  lds_u32_t;
typedef const __attribute__((address_space(1))) unsigned int glb_u32_t;

__device__ __forceinline__ float iou_pair_r(const float* b, const float* g) {
    const float inv_s = 1.0f / 7.0f;
    float x1 = b[0] * inv_s - b[2] * 0.5f;
    float y1 = b[1] * inv_s - b[3] * 0.5f;
    float x2 = b[0] * inv_s + b[2] * 0.5f;
    float y2 = b[1] * inv_s + b[3] * 0.5f;
    float u1 = g[0] * inv_s - g[2] * 0.5f;
    float v1 = g[1] * inv_s - g[3] * 0.5f;
    float u2 = g[0] * inv_s + g[2] * 0.5f;
    float v2 = g[1] * inv_s + g[3] * 0.5f;
    float a1 = (x2 - x1) * (y2 - y1);
    float a2 = (u2 - u1) * (v2 - v1);
    float left   = fmaxf(x1, u1);
    float right  = fminf(x2, u2);
    float top    = fmaxf(y1, v1);
    float bottom = fminf(y2, v2);
    bool valid = (left < right) && (top < bottom);
    float inter = valid ? (right - left) * (bottom - top) : 0.0f;
    float uni = a1 + a2 - inter;
    return valid ? inter / uni : 0.0f;
}

__device__ __forceinline__ float cell_loss(const float* p, const float* l) {
    float conf_lab = l[4];
    float coord_m = (conf_lab > 0.0f) ? 1.0f : 0.0f;
    float noobj_m = (conf_lab == 0.0f) ? 1.0f : 0.0f;

    float acc_noobj = noobj_m * (p[4] * p[4] + p[9] * p[9]);

    float class_s = 0.0f;
    #pragma unroll
    for (int k = 10; k < 26; ++k) {
        float d = p[k] - l[k];
        class_s += d * d;
    }

    float iou1 = iou_pair_r(p + 0, l);
    float iou2 = iou_pair_r(p + 5, l);
    bool pick1 = iou1 > iou2;

    float s0 = pick1 ? p[0] : p[5];
    float s1 = pick1 ? p[1] : p[6];
    float s2 = pick1 ? p[2] : p[7];
    float s3 = pick1 ? p[3] : p[8];
    float dx = s0 - l[0];
    float dy = s1 - l[1];
    float dw = sqrtf(s2) - sqrtf(l[2]);
    float dh = sqrtf(s3) - sqrtf(l[3]);
    float coord_cell = dx * dx + dy * dy + dw * dw + dh * dh;

    float csel   = pick1 ? p[4] : p[9];
    float iousel = pick1 ? iou1 : iou2;
    float t = csel - iousel;
    float obj_c = t * t;

    float cother = pick1 ? p[9] : p[4];
    acc_noobj += coord_m * cother * cother;

    return 5.0f * coord_m * coord_cell
         + coord_m * obj_c
         + 0.5f * acc_noobj
         + coord_m * class_s;
}

// 1 wave per block; per-wave double-buffered DMA pipeline, no __syncthreads.
// Each wave stages exactly the cells it computes, so a per-wave counted
// s_waitcnt vmcnt(N) is a correct fence (26 DMA issues per tile: 13 x 1KB
// chunks per array). vmcnt(26) after prefetching the next tile leaves the
// next tile's loads in flight while computing the current one.
__global__ __launch_bounds__(64) void yolo_loss_main(
        const float* __restrict__ predict,
        const float* __restrict__ label,
        float* __restrict__ partials,
        int n_tiles) {
    __shared__ float lds[2][2][TILE_FLOATS];   // [buf][arr][floats] = 52 KB
    const int lane = threadIdx.x;
    const int bid  = blockIdx.x;
    const int nb   = gridDim.x;

    auto stage = [&](int tile, int b) {
        const char* gp = (const char*)(predict + (long long)tile * TILE_FLOATS);
        const char* gl = (const char*)(label   + (long long)tile * TILE_FLOATS);
        char* dp = (char*)&lds[b][0][0];
        char* dl = (char*)&lds[b][1][0];
        #pragma unroll
        for (int c = 0; c < 13; ++c) {
            int off = c * 1024 + lane * 16;
            __builtin_amdgcn_global_load_lds(
                (glb_u32_t*)(gp + off), (lds_u32_t*)(dp + off), 16, 0, 0);
            __builtin_amdgcn_global_load_lds(
                (glb_u32_t*)(gl + off), (lds_u32_t*)(dl + off), 16, 0, 0);
        }
    };

    float partial = 0.0f;
    int buf = 0;
    if (bid < n_tiles) stage(bid, 0);

    for (int t = bid; t < n_tiles; t += nb) {
        int tn = t + nb;
        if (tn < n_tiles) {
            stage(tn, buf ^ 1);
            asm volatile("s_waitcnt vmcnt(26)" ::: "memory");  // tile t landed
        } else {
            asm volatile("s_waitcnt vmcnt(0)" ::: "memory");   // drain
        }
        __builtin_amdgcn_sched_barrier(0);

        #pragma unroll
        for (int h = 0; h < 2; ++h) {
            int cell = lane + 64 * h;   // stride-104B lanes -> 4-way LDS conflict (acceptable)
            float p[NCH], l[NCH];
            const float2* pv = (const float2*)&lds[buf][0][cell * NCH];
            const float2* lv = (const float2*)&lds[buf][1][cell * NCH];
            #pragma unroll
            for (int k = 0; k < 13; ++k) {
                float2 a  = pv[k]; p[2 * k] = a.x;  p[2 * k + 1] = a.y;
                float2 b2 = lv[k]; l[2 * k] = b2.x; l[2 * k + 1] = b2.y;
            }
            partial += cell_loss(p, l);
        }
        buf ^= 1;
    }

    #pragma unroll
    for (int off = 32; off > 0; off >>= 1)
        partial += __shfl_down(partial, off, 64);
    if (lane == 0) partials[bid] = partial;
}

__global__ __launch_bounds__(256) void yolo_loss_finalize(
        const float* __restrict__ partials, int nparts,
        const float* __restrict__ predict,
        const float* __restrict__ label,
        int tail_start, int n_cells, float inv_n,
        float* __restrict__ out) {
    float s = 0.0f;
    for (int i = threadIdx.x; i < nparts; i += 256) s += partials[i];

    // tail cells (n_cells % TCELLS) — scalar path, empty for B=8192
    for (int c = tail_start + threadIdx.x; c < n_cells; c += 256) {
        float p[NCH], l[NCH];
        const float* pp = predict + (long long)c * NCH;
        const float* ll = label   + (long long)c * NCH;
        #pragma unroll
        for (int k = 0; k < NCH; ++k) { p[k] = pp[k]; l[k] = ll[k]; }
        s += cell_loss(p, l);
    }

    #pragma unroll
    for (int off = 32; off > 0; off >>= 1)
        s += __shfl_down(s, off, 64);
    __shared__ float wsum[4];
    if ((threadIdx.x & 63) == 0) wsum[threadIdx.x >> 6] = s;
    __syncthreads();
    if (threadIdx.x == 0)
        out[0] = (wsum[0] + wsum[1] + wsum[2] + wsum[3]) * inv_n;
}

extern "C" void kernel_launch(void* const* d_in, const int* in_sizes, int n_in,
                              void* d_out, int out_size, void* d_ws, size_t ws_size,
                              hipStream_t stream) {
    const float* predict = (const float*)d_in[0];
    const float* label   = (const float*)d_in[1];
    float* out = (float*)d_out;
    float* partials = (float*)d_ws;

    int total   = in_sizes[0];           // B*7*7*26
    int n_cells = total / NCH;           // B*49
    int N = n_cells / 49;                // batch size
    int n_tiles = n_cells / TCELLS;      // 3136 for B=8192 (exact)
    int tail_start = n_tiles * TCELLS;

    int grid_main = n_tiles < GRID_MAIN ? (n_tiles > 0 ? n_tiles : 1) : GRID_MAIN;

    yolo_loss_main<<<grid_main, 64, 0, stream>>>(predict, label, partials, n_tiles);
    yolo_loss_finalize<<<1, 256, 0, stream>>>(partials, grid_main,
                                              predict, label,
                                              tail_start, n_cells,
                                              1.0f / (float)N, out);
}

// Round 12
// 104.254 us; speedup vs baseline: 1.0946x; 1.0162x over previous
//
#include <hip/hip_runtime.h>

#define NCH 26
#define CPB 128          // cells per block
#define THREADS 128      // 2 waves
#define TILE_FLOATS (CPB * NCH)        // 3328 floats = 13312 B per array

typedef __attribute__((address_space(3))) unsigned int  lds_u32_t;
typedef const __attribute__((address_space(1))) unsigned int glb_u32_t;

__device__ __forceinline__ float iou_pair_r(const float* b, const float* g) {
    const float inv_s = 1.0f / 7.0f;
    float x1 = b[0] * inv_s - b[2] * 0.5f;
    float y1 = b[1] * inv_s - b[3] * 0.5f;
    float x2 = b[0] * inv_s + b[2] * 0.5f;
    float y2 = b[1] * inv_s + b[3] * 0.5f;
    float u1 = g[0] * inv_s - g[2] * 0.5f;
    float v1 = g[1] * inv_s - g[3] * 0.5f;
    float u2 = g[0] * inv_s + g[2] * 0.5f;
    float v2 = g[1] * inv_s + g[3] * 0.5f;
    float a1 = (x2 - x1) * (y2 - y1);
    float a2 = (u2 - u1) * (v2 - v1);
    float left   = fmaxf(x1, u1);
    float right  = fminf(x2, u2);
    float top    = fmaxf(y1, v1);
    float bottom = fminf(y2, v2);
    bool valid = (left < right) && (top < bottom);
    float inter = valid ? (right - left) * (bottom - top) : 0.0f;
    float uni = a1 + a2 - inter;
    return valid ? inter / uni : 0.0f;
}

__global__ __launch_bounds__(THREADS) void yolo_loss_main(
        const float* __restrict__ predict,
        const float* __restrict__ label,
        float* __restrict__ partials,
        int n_cells) {
    __shared__ float sp[TILE_FLOATS];   // 13312 B
    __shared__ float sl[TILE_FLOATS];   // 13312 B  -> 26.6 KB total, 6 blocks/CU

    const int tid = threadIdx.x;
    const int bid = blockIdx.x;
    const int wave = tid >> 6;          // 0 or 1
    const int lane = tid & 63;
    const long long base = (long long)bid * TILE_FLOATS;   // float index
    const long long total = (long long)n_cells * NCH;

    if (base + TILE_FLOATS <= total) {
        // Direct global->LDS DMA (width 16), linear layout. 13 x 1KB chunks
        // per array; wave 0 stages predict, wave 1 stages label.
        const char* gsrc = (wave == 0) ? (const char*)(predict + base)
                                       : (const char*)(label + base);
        char* ldst = (wave == 0) ? (char*)sp : (char*)sl;
        #pragma unroll
        for (int c = 0; c < 13; ++c) {
            int off = c * 1024 + lane * 16;
            __builtin_amdgcn_global_load_lds(
                (glb_u32_t*)(gsrc + off), (lds_u32_t*)(ldst + off), 16, 0, 0);
        }
    } else {
        // tail block (not hit for B=8192): guarded scalar staging
        for (int i = tid; i < TILE_FLOATS; i += THREADS) {
            long long g = base + i;
            sp[i] = (g < total) ? predict[g] : 0.0f;
            sl[i] = (g < total) ? label[g] : 0.0f;
        }
    }
    __syncthreads();   // compiler emits s_waitcnt vmcnt(0) before s_barrier

    float partial = 0.0f;
    long long cell = (long long)bid * CPB + tid;
    if (cell < n_cells) {
        // vectorized LDS->reg: 13 x float2 per array (104B stride, 8-aligned)
        float p[NCH], l[NCH];
        const float2* pv = (const float2*)&sp[tid * NCH];
        const float2* lv = (const float2*)&sl[tid * NCH];
        #pragma unroll
        for (int k = 0; k < 13; ++k) {
            float2 a = pv[k]; p[2 * k] = a.x; p[2 * k + 1] = a.y;
            float2 b = lv[k]; l[2 * k] = b.x; l[2 * k + 1] = b.y;
        }

        float conf_lab = l[4];
        float coord_m = (conf_lab > 0.0f) ? 1.0f : 0.0f;
        float noobj_m = (conf_lab == 0.0f) ? 1.0f : 0.0f;

        float acc_noobj = noobj_m * (p[4] * p[4] + p[9] * p[9]);

        float class_s = 0.0f;
        #pragma unroll
        for (int k = 10; k < 26; ++k) {
            float d = p[k] - l[k];
            class_s += d * d;
        }

        float iou1 = iou_pair_r(p + 0, l);
        float iou2 = iou_pair_r(p + 5, l);
        bool pick1 = iou1 > iou2;

        float s0 = pick1 ? p[0] : p[5];
        float s1 = pick1 ? p[1] : p[6];
        float s2 = pick1 ? p[2] : p[7];
        float s3 = pick1 ? p[3] : p[8];
        float dx = s0 - l[0];
        float dy = s1 - l[1];
        float dw = sqrtf(s2) - sqrtf(l[2]);
        float dh = sqrtf(s3) - sqrtf(l[3]);
        float coord_cell = dx * dx + dy * dy + dw * dw + dh * dh;

        float csel   = pick1 ? p[4] : p[9];
        float iousel = pick1 ? iou1 : iou2;
        float t = csel - iousel;
        float obj_c = t * t;

        float cother = pick1 ? p[9] : p[4];
        acc_noobj += coord_m * cother * cother;

        partial = 5.0f * coord_m * coord_cell
                + coord_m * obj_c
                + 0.5f * acc_noobj
                + coord_m * class_s;
    }

    // block reduction: wave64 shuffle, then cross-wave LDS (2 waves)
    #pragma unroll
    for (int off = 32; off > 0; off >>= 1)
        partial += __shfl_down(partial, off, 64);

    __shared__ float wsum[THREADS / 64];
    if ((tid & 63) == 0) wsum[tid >> 6] = partial;
    __syncthreads();
    if (tid == 0)
        partials[bid] = wsum[0] + wsum[1];
}

__global__ __launch_bounds__(256) void yolo_loss_finalize(
        const float* __restrict__ partials, int n, float inv_n,
        float* __restrict__ out) {
    float s = 0.0f;
    for (int i = threadIdx.x; i < n; i += 256) s += partials[i];
    #pragma unroll
    for (int off = 32; off > 0; off >>= 1)
        s += __shfl_down(s, off, 64);
    __shared__ float wsum[4];
    if ((threadIdx.x & 63) == 0) wsum[threadIdx.x >> 6] = s;
    __syncthreads();
    if (threadIdx.x == 0)
        out[0] = (wsum[0] + wsum[1] + wsum[2] + wsum[3]) * inv_n;
}

extern "C" void kernel_launch(void* const* d_in, const int* in_sizes, int n_in,
                              void* d_out, int out_size, void* d_ws, size_t ws_size,
                              hipStream_t stream) {
    const float* predict = (const float*)d_in[0];
    const float* label   = (const float*)d_in[1];
    float* out = (float*)d_out;
    float* partials = (float*)d_ws;

    int total   = in_sizes[0];         // B*7*7*26
    int n_cells = total / NCH;         // B*49
    int N = n_cells / 49;              // batch size
    int nblocks = (n_cells + CPB - 1) / CPB;   // 3136 for B=8192

    yolo_loss_main<<<nblocks, THREADS, 0, stream>>>(predict, label, partials, n_cells);
    yolo_loss_finalize<<<1, 256, 0, stream>>>(partials, nblocks, 1.0f / (float)N, out);
}

// Round 14
// 102.113 us; speedup vs baseline: 1.1176x; 1.0210x over previous
//
#include <hip/hip_runtime.h>

#define NCH 26
#define CPB 256          // cells per block
#define THREADS 256
#define TILE_FLOATS (CPB * NCH)        // 6656 floats per array

typedef __attribute__((address_space(3))) unsigned int  lds_u32_t;
typedef const __attribute__((address_space(1))) unsigned int glb_u32_t;

__device__ __forceinline__ float iou_pair_r(const float* b, const float* g) {
    const float inv_s = 1.0f / 7.0f;
    float x1 = b[0] * inv_s - b[2] * 0.5f;
    float y1 = b[1] * inv_s - b[3] * 0.5f;
    float x2 = b[0] * inv_s + b[2] * 0.5f;
    float y2 = b[1] * inv_s + b[3] * 0.5f;
    float u1 = g[0] * inv_s - g[2] * 0.5f;
    float v1 = g[1] * inv_s - g[3] * 0.5f;
    float u2 = g[0] * inv_s + g[2] * 0.5f;
    float v2 = g[1] * inv_s + g[3] * 0.5f;
    float a1 = (x2 - x1) * (y2 - y1);
    float a2 = (u2 - u1) * (v2 - v1);
    float left   = fmaxf(x1, u1);
    float right  = fminf(x2, u2);
    float top    = fmaxf(y1, v1);
    float bottom = fminf(y2, v2);
    bool valid = (left < right) && (top < bottom);
    float inter = valid ? (right - left) * (bottom - top) : 0.0f;
    float uni = a1 + a2 - inter;
    return valid ? inter / uni : 0.0f;
}

__global__ __launch_bounds__(THREADS) void yolo_loss_main(
        const float* __restrict__ predict,
        const float* __restrict__ label,
        float* __restrict__ partials,
        int n_cells) {
    __shared__ float sp[TILE_FLOATS];
    __shared__ float sl[TILE_FLOATS];

    const int tid = threadIdx.x;
    const int bid = blockIdx.x;
    const int wave = tid >> 6;
    const int lane = tid & 63;
    const long long base = (long long)bid * TILE_FLOATS;   // float index
    const long long total = (long long)n_cells * NCH;

    if (base + TILE_FLOATS <= total) {
        // Direct global->LDS DMA (width 16), linear layout: chunk c covers
        // bytes [c*1024, c*1024+1024) in both the global tile and LDS
        // (wave-uniform base + lane*16 — exactly the supported pattern).
        const char* gp = (const char*)(predict + base);
        const char* gl = (const char*)(label + base);
        #pragma unroll
        for (int c = 0; c < 7; ++c) {
            int chunk = wave + 4 * c;          // 4 waves cover 26 chunks
            if (chunk < 26) {
                int off = chunk * 1024 + lane * 16;
                __builtin_amdgcn_global_load_lds(
                    (glb_u32_t*)(gp + off),
                    (lds_u32_t*)((char*)sp + off), 16, 0, 0);
                __builtin_amdgcn_global_load_lds(
                    (glb_u32_t*)(gl + off),
                    (lds_u32_t*)((char*)sl + off), 16, 0, 0);
            }
        }
    } else {
        // tail block (not hit for B=8192): guarded scalar staging
        for (int i = tid; i < TILE_FLOATS; i += THREADS) {
            long long g = base + i;
            sp[i] = (g < total) ? predict[g] : 0.0f;
            sl[i] = (g < total) ? label[g] : 0.0f;
        }
    }
    __syncthreads();   // compiler emits s_waitcnt vmcnt(0) before s_barrier

    float partial = 0.0f;
    long long cell = (long long)bid * CPB + tid;
    if (cell < n_cells) {
        // vectorized LDS->reg: 13 x float2 per array (104B stride, 8-aligned)
        float p[NCH], l[NCH];
        const float2* pv = (const float2*)&sp[tid * NCH];
        const float2* lv = (const float2*)&sl[tid * NCH];
        #pragma unroll
        for (int k = 0; k < 13; ++k) {
            float2 a = pv[k]; p[2 * k] = a.x; p[2 * k + 1] = a.y;
            float2 b = lv[k]; l[2 * k] = b.x; l[2 * k + 1] = b.y;
        }

        float conf_lab = l[4];
        float coord_m = (conf_lab > 0.0f) ? 1.0f : 0.0f;
        float noobj_m = (conf_lab == 0.0f) ? 1.0f : 0.0f;

        float acc_noobj = noobj_m * (p[4] * p[4] + p[9] * p[9]);

        float class_s = 0.0f;
        #pragma unroll
        for (int k = 10; k < 26; ++k) {
            float d = p[k] - l[k];
            class_s += d * d;
        }

        float iou1 = iou_pair_r(p + 0, l);
        float iou2 = iou_pair_r(p + 5, l);
        bool pick1 = iou1 > iou2;

        float s0 = pick1 ? p[0] : p[5];
        float s1 = pick1 ? p[1] : p[6];
        float s2 = pick1 ? p[2] : p[7];
        float s3 = pick1 ? p[3] : p[8];
        float dx = s0 - l[0];
        float dy = s1 - l[1];
        float dw = sqrtf(s2) - sqrtf(l[2]);
        float dh = sqrtf(s3) - sqrtf(l[3]);
        float coord_cell = dx * dx + dy * dy + dw * dw + dh * dh;

        float csel   = pick1 ? p[4] : p[9];
        float iousel = pick1 ? iou1 : iou2;
        float t = csel - iousel;
        float obj_c = t * t;

        float cother = pick1 ? p[9] : p[4];
        acc_noobj += coord_m * cother * cother;

        partial = 5.0f * coord_m * coord_cell
                + coord_m * obj_c
                + 0.5f * acc_noobj
                + coord_m * class_s;
    }

    // block reduction: wave64 shuffle, then cross-wave LDS
    #pragma unroll
    for (int off = 32; off > 0; off >>= 1)
        partial += __shfl_down(partial, off, 64);

    __shared__ float wsum[THREADS / 64];
    if ((tid & 63) == 0) wsum[tid >> 6] = partial;
    __syncthreads();
    if (tid == 0) {
        float s = 0.0f;
        #pragma unroll
        for (int w = 0; w < THREADS / 64; ++w) s += wsum[w];
        partials[bid] = s;
    }
}

__global__ __launch_bounds__(256) void yolo_loss_finalize(
        const float* __restrict__ partials, int n, float inv_n,
        float* __restrict__ out) {
    float s = 0.0f;
    for (int i = threadIdx.x; i < n; i += 256) s += partials[i];
    #pragma unroll
    for (int off = 32; off > 0; off >>= 1)
        s += __shfl_down(s, off, 64);
    __shared__ float wsum[4];
    if ((threadIdx.x & 63) == 0) wsum[threadIdx.x >> 6] = s;
    __syncthreads();
    if (threadIdx.x == 0)
        out[0] = (wsum[0] + wsum[1] + wsum[2] + wsum[3]) * inv_n;
}

extern "C" void kernel_launch(void* const* d_in, const int* in_sizes, int n_in,
                              void* d_out, int out_size, void* d_ws, size_t ws_size,
                              hipStream_t stream) {
    const float* predict = (const float*)d_in[0];
    const float* label   = (const float*)d_in[1];
    float* out = (float*)d_out;
    float* partials = (float*)d_ws;

    int total   = in_sizes[0];         // B*7*7*26
    int n_cells = total / NCH;         // B*49
    int N = n_cells / 49;              // batch size
    int nblocks = (n_cells + CPB - 1) / CPB;

    yolo_loss_main<<<nblocks, THREADS, 0, stream>>>(predict, label, partials, n_cells);
    yolo_loss_finalize<<<1, 256, 0, stream>>>(partials, nblocks, 1.0f / (float)N, out);
}